// Round 1
// baseline (1363.164 us; speedup 1.0000x reference)
//
#include <hip/hip_runtime.h>

#define N_DIM       64
#define N_IMAGES    1024
#define ROWS_PER_BLOCK 4096
#define THREADS     256

// Phase A: per-block contiguous row chunk.
//  - copies image_id -> float into d_out id region (vectorized int4->float4)
//  - computes partial segment sums/counts with register accumulation,
//    flushing to global atomics only on id change (ids are sorted, so
//    ~1-2 flushes per thread).
__global__ __launch_bounds__(THREADS) void ImageAverage_phaseA(
    const float* __restrict__ x,
    const int*   __restrict__ ids,
    float*       __restrict__ accum,     // [N_IMAGES * N_DIM] fp32, pre-zeroed
    int*         __restrict__ counts,    // [N_IMAGES] int32, pre-zeroed
    float*       __restrict__ out_id)    // [n_reflns] float copy of ids
{
    const int t = threadIdx.x;
    const long long blockRow0 = (long long)blockIdx.x * ROWS_PER_BLOCK;

    // ---- id copy: int4 -> float4, fully coalesced ----
    {
        const int4* idv  = (const int4*)(ids + blockRow0);
        float4*     outv = (float4*)(out_id + blockRow0);
        const int niter = ROWS_PER_BLOCK / 4 / THREADS;   // 4
        #pragma unroll
        for (int k = 0; k < niter; ++k) {
            int4 v = idv[k * THREADS + t];
            outv[k * THREADS + t] =
                make_float4((float)v.x, (float)v.y, (float)v.z, (float)v.w);
        }
    }

    // ---- segment sums ----
    // thread -> 4 consecutive dims (float4), rows strided by 16
    const int dimGroup = t & 15;        // 0..15
    const int d0       = dimGroup * 4;  // starting dim
    const int rowOff   = t >> 4;        // 0..15
    const bool isCounter = (dimGroup == 0);   // exactly one thread per row residue

    float4 sum = make_float4(0.f, 0.f, 0.f, 0.f);
    int    cnt = 0;

    long long row = blockRow0 + rowOff;
    int cur = ids[row];

    #pragma unroll 4
    for (int it = 0; it < ROWS_PER_BLOCK / 16; ++it, row += 16) {
        const int id = ids[row];
        if (id != cur) {
            float* a = accum + (long long)cur * N_DIM + d0;
            atomicAdd(a + 0, sum.x);
            atomicAdd(a + 1, sum.y);
            atomicAdd(a + 2, sum.z);
            atomicAdd(a + 3, sum.w);
            if (isCounter) atomicAdd(&counts[cur], cnt);
            sum = make_float4(0.f, 0.f, 0.f, 0.f);
            cnt = 0;
            cur = id;
        }
        const float4 v = *(const float4*)(x + row * N_DIM + d0);
        sum.x += v.x; sum.y += v.y; sum.z += v.z; sum.w += v.w;
        cnt++;
    }
    // final flush
    {
        float* a = accum + (long long)cur * N_DIM + d0;
        atomicAdd(a + 0, sum.x);
        atomicAdd(a + 1, sum.y);
        atomicAdd(a + 2, sum.z);
        atomicAdd(a + 3, sum.w);
        if (isCounter) atomicAdd(&counts[cur], cnt);
    }
}

// Phase B: averaged = accum / max(count,1); counts -> float tail
__global__ __launch_bounds__(THREADS) void ImageAverage_phaseB(
    const float* __restrict__ accum,
    const int*   __restrict__ counts,
    float*       __restrict__ out_avg,     // [N_IMAGES * N_DIM]
    float*       __restrict__ out_counts)  // [N_IMAGES]
{
    const int i = blockIdx.x * blockDim.x + threadIdx.x;
    if (i < N_IMAGES * N_DIM) {
        const int img = i >> 6;   // / N_DIM
        const int c = counts[img];
        const float denom = (float)(c > 0 ? c : 1);
        out_avg[i] = accum[i] / denom;
    }
    if (i < N_IMAGES) {
        out_counts[i] = (float)counts[i];
    }
}

extern "C" void kernel_launch(void* const* d_in, const int* in_sizes, int n_in,
                              void* d_out, int out_size, void* d_ws, size_t ws_size,
                              hipStream_t stream) {
    const float* x   = (const float*)d_in[0];
    const int*   ids = (const int*)d_in[1];
    const int n_reflns = in_sizes[1];          // 4194304

    // output layout (all float32): [avg 1024*64][id copy n_reflns][counts 1024]
    float* out_avg    = (float*)d_out;
    float* out_id     = out_avg + (size_t)N_IMAGES * N_DIM;
    float* out_counts = out_id + (size_t)n_reflns;

    // workspace: [accum 1024*64 fp32][counts 1024 int32]
    float* accum  = (float*)d_ws;
    int*   counts = (int*)((char*)d_ws + (size_t)N_IMAGES * N_DIM * sizeof(float));

    hipMemsetAsync(d_ws, 0,
                   (size_t)N_IMAGES * N_DIM * sizeof(float) + (size_t)N_IMAGES * sizeof(int),
                   stream);

    const int gridA = n_reflns / ROWS_PER_BLOCK;   // 1024
    ImageAverage_phaseA<<<gridA, THREADS, 0, stream>>>(x, ids, accum, counts, out_id);

    const int nB = N_IMAGES * N_DIM;               // 65536
    ImageAverage_phaseB<<<(nB + THREADS - 1) / THREADS, THREADS, 0, stream>>>(
        accum, counts, out_avg, out_counts);
}

// Round 2
// 1329.738 us; speedup vs baseline: 1.0251x; 1.0251x over previous
//
#include <hip/hip_runtime.h>

#define N_DIM          64
#define N_IMAGES       1024
#define ROWS_PER_BLOCK 2048
#define THREADS        256

typedef float v4f __attribute__((ext_vector_type(4)));
typedef int   v4i __attribute__((ext_vector_type(4)));

// Phase A: per-block contiguous chunk of 2048 rows.
//  - id copy (int4 -> float4, nontemporal stores)
//  - segment sums with register accumulation; sorted ids => group-of-4 fast
//    path guarded by a single compare on the group's LAST id (sorted order
//    guarantees cur <= id[k] <= id[last], so id[last]==cur => all == cur).
//    The fast path has no flush-dependent control flow, so the 4 float4
//    loads pipeline without vmcnt(0) drains.
__global__ __launch_bounds__(THREADS) void ImageAverage_phaseA(
    const float* __restrict__ x,
    const int*   __restrict__ ids,
    float*       __restrict__ accum,     // [N_IMAGES * N_DIM] fp32, pre-zeroed
    int*         __restrict__ counts,    // [N_IMAGES] int32, pre-zeroed
    float*       __restrict__ out_id)    // [n_reflns] float copy of ids
{
    const int t = threadIdx.x;
    const long long blockRow0 = (long long)blockIdx.x * ROWS_PER_BLOCK;

    // ---- id copy: fully coalesced, nontemporal ----
    {
        const v4i* idv  = (const v4i*)(ids + blockRow0);
        v4f*       outv = (v4f*)(out_id + blockRow0);
        const int niter = ROWS_PER_BLOCK / 4 / THREADS;   // 2
        #pragma unroll
        for (int k = 0; k < niter; ++k) {
            v4i v = idv[k * THREADS + t];
            v4f f;
            f.x = (float)v.x; f.y = (float)v.y; f.z = (float)v.z; f.w = (float)v.w;
            __builtin_nontemporal_store(f, &outv[k * THREADS + t]);
        }
    }

    // ---- segment sums ----
    // thread -> 4 consecutive dims (float4), rows strided by 16
    const int dimGroup = t & 15;        // 0..15
    const int d0       = dimGroup * 4;  // starting dim
    const int rowOff   = t >> 4;        // 0..15
    const bool isCounter = (dimGroup == 0);

    v4f sum = {0.f, 0.f, 0.f, 0.f};
    int cnt = 0;

    long long row = blockRow0 + rowOff;
    int cur = ids[row];

    const int NGROUPS = ROWS_PER_BLOCK / 16 / 4;   // 32 groups of 4 sampled rows
    for (int g = 0; g < NGROUPS; ++g, row += 64) {
        const int idLast = ids[row + 48];
        if (idLast == cur) {
            // fast path: all 4 rows belong to cur
            const v4f a = __builtin_nontemporal_load((const v4f*)(x + (row     ) * N_DIM + d0));
            const v4f b = __builtin_nontemporal_load((const v4f*)(x + (row + 16) * N_DIM + d0));
            const v4f c = __builtin_nontemporal_load((const v4f*)(x + (row + 32) * N_DIM + d0));
            const v4f d = __builtin_nontemporal_load((const v4f*)(x + (row + 48) * N_DIM + d0));
            sum += (a + b) + (c + d);
            cnt += 4;
        } else {
            // slow path: at least one boundary inside the group (rare)
            #pragma unroll
            for (int k = 0; k < 4; ++k) {
                const long long r = row + 16 * k;
                const int id = ids[r];
                if (id != cur) {
                    float* a = accum + (long long)cur * N_DIM + d0;
                    atomicAdd(a + 0, sum.x);
                    atomicAdd(a + 1, sum.y);
                    atomicAdd(a + 2, sum.z);
                    atomicAdd(a + 3, sum.w);
                    if (isCounter) atomicAdd(&counts[cur], cnt);
                    sum = (v4f){0.f, 0.f, 0.f, 0.f};
                    cnt = 0;
                    cur = id;
                }
                const v4f v = __builtin_nontemporal_load((const v4f*)(x + r * N_DIM + d0));
                sum += v;
                cnt++;
            }
        }
    }
    // final flush
    {
        float* a = accum + (long long)cur * N_DIM + d0;
        atomicAdd(a + 0, sum.x);
        atomicAdd(a + 1, sum.y);
        atomicAdd(a + 2, sum.z);
        atomicAdd(a + 3, sum.w);
        if (isCounter) atomicAdd(&counts[cur], cnt);
    }
}

// Phase B: averaged = accum / max(count,1); counts -> float tail
__global__ __launch_bounds__(THREADS) void ImageAverage_phaseB(
    const float* __restrict__ accum,
    const int*   __restrict__ counts,
    float*       __restrict__ out_avg,     // [N_IMAGES * N_DIM]
    float*       __restrict__ out_counts)  // [N_IMAGES]
{
    const int i = blockIdx.x * blockDim.x + threadIdx.x;
    if (i < N_IMAGES * N_DIM) {
        const int img = i >> 6;   // / N_DIM
        const int c = counts[img];
        const float denom = (float)(c > 0 ? c : 1);
        out_avg[i] = accum[i] / denom;
    }
    if (i < N_IMAGES) {
        out_counts[i] = (float)counts[i];
    }
}

extern "C" void kernel_launch(void* const* d_in, const int* in_sizes, int n_in,
                              void* d_out, int out_size, void* d_ws, size_t ws_size,
                              hipStream_t stream) {
    const float* x   = (const float*)d_in[0];
    const int*   ids = (const int*)d_in[1];
    const int n_reflns = in_sizes[1];          // 4194304

    // output layout (all float32): [avg 1024*64][id copy n_reflns][counts 1024]
    float* out_avg    = (float*)d_out;
    float* out_id     = out_avg + (size_t)N_IMAGES * N_DIM;
    float* out_counts = out_id + (size_t)n_reflns;

    // workspace: [accum 1024*64 fp32][counts 1024 int32]
    float* accum  = (float*)d_ws;
    int*   counts = (int*)((char*)d_ws + (size_t)N_IMAGES * N_DIM * sizeof(float));

    hipMemsetAsync(d_ws, 0,
                   (size_t)N_IMAGES * N_DIM * sizeof(float) + (size_t)N_IMAGES * sizeof(int),
                   stream);

    const int gridA = n_reflns / ROWS_PER_BLOCK;   // 2048 -> 8 blocks/CU, 32 waves/CU
    ImageAverage_phaseA<<<gridA, THREADS, 0, stream>>>(x, ids, accum, counts, out_id);

    const int nB = N_IMAGES * N_DIM;               // 65536
    ImageAverage_phaseB<<<(nB + THREADS - 1) / THREADS, THREADS, 0, stream>>>(
        accum, counts, out_avg, out_counts);
}